// Round 9
// baseline (369.513 us; speedup 1.0000x reference)
//
#include <hip/hip_runtime.h>

// BitLinear: LN (no affine) -> global absmax int8 quant -> q @ sign(W-mean(W))^T
//   -> * (maxval/128 * mean|W|) + bias
// x: [4,2048,2048] f32 -> M=8192,K=2048 ; W: [8192,2048] -> N=8192 ; out f32 [8192,8192]

using i32x4 = __attribute__((ext_vector_type(4))) int;
using i32x16 = __attribute__((ext_vector_type(16))) int;

typedef const __attribute__((address_space(1))) void cg_void;
typedef __attribute__((address_space(3))) void lds_void;

#define K_DIM 2048
#define N_DIM 8192
#define M_DIM 8192
#define NELEM_W 16777216   // 8192*2048

// ws layout: scal@0 ([0]=absmax f32, [1]=wmean, [2]=beta); part@1024; mu@32768;
//            rstd@65536; rowmax@98304; q@131072; wq@131072+16M

// ---- fused pass1: W sum/abs-sum partials (blocks 0..1023) + LN stats (1024..9215) ----
__global__ __launch_bounds__(256) void pass1(const float* __restrict__ x,
                                             const float4* __restrict__ w4,
                                             float* __restrict__ mu_arr,
                                             float* __restrict__ rstd_arr,
                                             float* __restrict__ rowmax,
                                             double2* __restrict__ part) {
    __shared__ double sbd[8];
    __shared__ float sb1[4];
    __shared__ float sb2[8];
    const int bid = blockIdx.x, t = threadIdx.x;
    const int lane = t & 63, wv = t >> 6;
    if (bid < 1024) {
        double s = 0.0, a = 0.0;
        for (int i = bid * 256 + t; i < NELEM_W / 4; i += 1024 * 256) {
            float4 v = w4[i];
            s += (double)v.x + (double)v.y + (double)v.z + (double)v.w;
            a += fabs((double)v.x) + fabs((double)v.y) + fabs((double)v.z) + fabs((double)v.w);
        }
        for (int o = 32; o; o >>= 1) { s += __shfl_xor(s, o); a += __shfl_xor(a, o); }
        if (lane == 0) { sbd[wv] = s; sbd[4 + wv] = a; }
        __syncthreads();
        if (t == 0) {
            double2 r;
            r.x = sbd[0] + sbd[1] + sbd[2] + sbd[3];
            r.y = sbd[4] + sbd[5] + sbd[6] + sbd[7];
            part[bid] = r;
        }
    } else {
        const int row = bid - 1024;
        const float4* xr = (const float4*)x + (size_t)row * 512;
        float4 v0 = xr[t], v1 = xr[t + 256];
        float s = v0.x + v0.y + v0.z + v0.w + v1.x + v1.y + v1.z + v1.w;
        for (int o = 32; o; o >>= 1) s += __shfl_xor(s, o);
        if (lane == 0) sb1[wv] = s;
        __syncthreads();
        float mu = (sb1[0] + sb1[1] + sb1[2] + sb1[3]) * (1.0f / 2048.0f);
        float ssq = 0.f, md = 0.f, d;
        d = v0.x - mu; ssq += d * d; md = fmaxf(md, fabsf(d));
        d = v0.y - mu; ssq += d * d; md = fmaxf(md, fabsf(d));
        d = v0.z - mu; ssq += d * d; md = fmaxf(md, fabsf(d));
        d = v0.w - mu; ssq += d * d; md = fmaxf(md, fabsf(d));
        d = v1.x - mu; ssq += d * d; md = fmaxf(md, fabsf(d));
        d = v1.y - mu; ssq += d * d; md = fmaxf(md, fabsf(d));
        d = v1.z - mu; ssq += d * d; md = fmaxf(md, fabsf(d));
        d = v1.w - mu; ssq += d * d; md = fmaxf(md, fabsf(d));
        for (int o = 32; o; o >>= 1) {
            ssq += __shfl_xor(ssq, o);
            md = fmaxf(md, __shfl_xor(md, o));
        }
        if (lane == 0) { sb2[wv] = ssq; sb2[4 + wv] = md; }
        __syncthreads();
        if (t == 0) {
            float var = (sb2[0] + sb2[1] + sb2[2] + sb2[3]) * (1.0f / 2048.0f);
            float rstd = 1.0f / sqrtf(var + 1e-5f);
            mu_arr[row] = mu;
            rstd_arr[row] = rstd;
            rowmax[row] = fmaxf(fmaxf(sb2[4], sb2[5]), fmaxf(sb2[6], sb2[7])) * rstd;
        }
    }
}

// ---- wred2: finalize wmean/beta + global absmax ----
__global__ __launch_bounds__(256) void wred2(const double2* __restrict__ part,
                                             const float* __restrict__ rowmax,
                                             unsigned* __restrict__ scal) {
    double s = 0.0, a = 0.0;
    float m = 0.f;
    const int t = threadIdx.x, lane = t & 63, wv = t >> 6;
    for (int i = t; i < 1024; i += 256) { double2 p = part[i]; s += p.x; a += p.y; }
    for (int i = t; i < 8192; i += 256) m = fmaxf(m, rowmax[i]);
    for (int o = 32; o; o >>= 1) {
        s += __shfl_xor(s, o); a += __shfl_xor(a, o);
        m = fmaxf(m, __shfl_xor(m, o));
    }
    __shared__ double sbd[8];
    __shared__ float sbm[4];
    if (lane == 0) { sbd[wv] = s; sbd[4 + wv] = a; sbm[wv] = m; }
    __syncthreads();
    if (t == 0) {
        double st = sbd[0] + sbd[1] + sbd[2] + sbd[3];
        double at = sbd[4] + sbd[5] + sbd[6] + sbd[7];
        ((float*)scal)[0] = fmaxf(fmaxf(sbm[0], sbm[1]), fmaxf(sbm[2], sbm[3]));
        ((float*)scal)[1] = (float)(st / (double)NELEM_W);  // wmean
        ((float*)scal)[2] = (float)(at / (double)NELEM_W);  // beta
    }
}

// ---- fused pass2: quant_w (blocks 0..1023) + quant_x (1024..9215) ----
__device__ __forceinline__ int sgn8(float d) { return (d > 0.f) ? 1 : ((d < 0.f) ? -1 : 0); }

__global__ __launch_bounds__(256) void pass2(const float* __restrict__ x,
                                             const float4* __restrict__ w4,
                                             const float* __restrict__ mu_arr,
                                             const float* __restrict__ rstd_arr,
                                             const unsigned* __restrict__ scal,
                                             signed char* __restrict__ q,
                                             int4* __restrict__ wq4) {
    const int bid = blockIdx.x, t = threadIdx.x;
    if (bid < 1024) {
        float wm = ((const float*)scal)[1];
        for (int i = bid * 256 + t; i < NELEM_W / 16; i += 1024 * 256) {
            int words[4];
            #pragma unroll
            for (int jj = 0; jj < 4; ++jj) {
                float4 v = w4[i * 4 + jj];
                int b0 = sgn8(v.x - wm) & 255, b1 = sgn8(v.y - wm) & 255;
                int b2 = sgn8(v.z - wm) & 255, b3 = sgn8(v.w - wm) & 255;
                words[jj] = b0 | (b1 << 8) | (b2 << 16) | (b3 << 24);
            }
            wq4[i] = make_int4(words[0], words[1], words[2], words[3]);
        }
    } else {
        const int row = bid - 1024;
        float mu = mu_arr[row], rstd = rstd_arr[row];
        float s = 128.0f / ((const float*)scal)[0];
        const float4* xr = (const float4*)x + (size_t)row * 512;
        float4 v0 = xr[2 * t], v1 = xr[2 * t + 1];
        float xs[8] = {v0.x, v0.y, v0.z, v0.w, v1.x, v1.y, v1.z, v1.w};
        int b[8];
        #pragma unroll
        for (int j = 0; j < 8; ++j) {
            float norm = (xs[j] - mu) * rstd;
            int qi = (int)rintf(norm * s);   // half-even == jnp.round; +128 wraps via &255
            b[j] = qi & 255;
        }
        int w0 = b[0] | (b[1] << 8) | (b[2] << 16) | (b[3] << 24);
        int w1 = b[4] | (b[5] << 8) | (b[6] << 16) | (b[7] << 24);
        ((int2*)(q + (size_t)row * 2048))[t] = make_int2(w0, w1);
    }
}

// ---- int8 GEMM v9: A-only LDS (new 2-bit-row perm), B direct global->VGPR ----
// 256x128 tile, BK=64, 8 waves (4Mx2N), per-wave 64x64 = 2x2 of 32x32, 32KB LDS,
// 2 blocks/CU. A LDS: packed 128B rows (tile rows r / r+128 share LDS row r&127);
// 16B slot = (half*4 + ks*2 + hi) ^ (R&7) ^ (((R>>3)&3)<<1)  [covers 8 bank-quads x2
// under both consecutive and interleaved quarter-wave groupings]. DMA dest linear,
// inverse perm in the per-lane global source (still 2x64B lines per 8 lanes).
// B skips LDS entirely: per-lane 16B global gathers (8KB/block B-panel lines stay
// L1-resident, 4x wave reuse) -> removes 40KB/block/K-tile of LDS traffic.
#define LD16(p) (*(const i32x4*)(p))
#define TILE_BYTES 16384   // A only per buffer

#define STAGE(koff, sbase)                                                                  \
    do {                                                                                    \
        __builtin_amdgcn_global_load_lds((cg_void*)(gA + (koff)),                           \
            (lds_void*)(lds + (sbase) + w * 2048), 16, 0, 0);                               \
        __builtin_amdgcn_global_load_lds((cg_void*)(gA + 8 * K_DIM + (koff)),               \
            (lds_void*)(lds + (sbase) + w * 2048 + 1024), 16, 0, 0);                        \
    } while (0)

__global__ __launch_bounds__(512, 4) void gemm_i8(const signed char* __restrict__ A,
                                                  const signed char* __restrict__ B,
                                                  const float* __restrict__ bias,
                                                  const unsigned* __restrict__ scal,
                                                  float* __restrict__ C) {
    __shared__ alignas(16) char lds[32768];    // 2 x A 16K
    const int t = threadIdx.x, w = t >> 6, lane = t & 63;

    // grid 2048 = 8 XCD x (4 m-panels x 64 n); A panel (512 KB) stays L2-hot per XCD.
    const int wg = blockIdx.x;
    const int xcd = wg & 7, idx = wg >> 3;
    const int bm = (xcd * 4 + (idx >> 6)) * 256;
    const int bn = (idx & 63) * 128;

    const int wr = w >> 1, wc = w & 1;         // wave grid 4M x 2N
    const int r32 = lane & 31, hi = lane >> 5; // 32x32 fragment coords

    // ---- A DMA source (inverse of perm layout) ----
    // load j (j=0,1): LDS row R = w*16 + j*8 + (lane>>3), slot s = lane&7;
    // u = s ^ (lane>>3) ^ (((w*2+j)&3)<<1); tile row = R + 128*(u>>2); col16 = u&3.
    const int g0 = lane >> 3, s0 = lane & 7;
    const int u0 = s0 ^ g0 ^ (((w * 2) & 3) << 1);
    const int u1 = s0 ^ g0 ^ (((w * 2 + 1) & 3) << 1);
    const int aRow0 = w * 16 + g0 + ((u0 >> 2) << 7);
    const int aRow1 = w * 16 + 8 + g0 + ((u1 >> 2) << 7);
    // bake per-lane column into two A pointers (one per load j)
    const signed char* gA  = A + (size_t)(bm + aRow0) * K_DIM + ((u0 & 3) << 4);
    const signed char* gA1 = A + (size_t)(bm + aRow1) * K_DIM + ((u1 & 3) << 4) - 8 * K_DIM;
    // (STAGE adds 8*K_DIM for load j=1; pre-subtract so both use same macro form)
    #define gA_J1 gA1

    // ---- B direct per-lane pointer: col = bn + wc*64 + nb*32 + r32, k-off hi*16 ----
    const signed char* gBf = B + (size_t)(bn + wc * 64 + r32) * K_DIM + hi * 16;

    // ---- A fragment read addressing ----
    // LDS row R = (wr&1)*64 + mb*32 + r32; slot = ((wr>>1)*4 + ks*2 + hi) ^ aperm,
    // aperm = (r32&7) ^ (((r32>>3)&3)<<1)   [mb,wr&1 contribute 0 mod 4 to R>>3]
    const char* aBase = lds + ((wr & 1) * 64 + r32) * 128;
    const int aperm = (r32 & 7) ^ (((r32 >> 3) & 3) << 1);
    const int aS0 = ((((wr >> 1) << 2) + hi) ^ aperm) << 4;        // ks=0
    const int aS1 = ((((wr >> 1) << 2) + 2 + hi) ^ aperm) << 4;    // ks=1

    const float scale = (((const float*)scal)[0] * (1.0f / 128.0f)) * ((const float*)scal)[2];

    i32x16 acc[2][2] = {};
    i32x4 af0[2], af1[2], bc[2][2];

    // prologue: tile 0 A -> buf0 (2 DMA in flight)
    {
        __builtin_amdgcn_global_load_lds((cg_void*)(gA), (lds_void*)(lds + w * 2048), 16, 0, 0);
        __builtin_amdgcn_global_load_lds((cg_void*)(gA1 + 8 * K_DIM),
                                         (lds_void*)(lds + w * 2048 + 1024), 16, 0, 0);
    }

    #pragma unroll 2
    for (int kt = 0; kt < 32; ++kt) {
        const int c = (kt & 1) * TILE_BYTES;
        // B for THIS tile: 4 global 16B gathers (latency hides under vmcnt+barrier+ds)
        #pragma unroll
        for (int nb = 0; nb < 2; ++nb)
            #pragma unroll
            for (int ks = 0; ks < 2; ++ks)
                bc[nb][ks] = LD16(gBf + (size_t)nb * 65536 + kt * 64 + ks * 32);
        if (kt < 31) {
            const int koff = (kt + 1) * 64;
            const int sb = ((kt + 1) & 1) * TILE_BYTES;
            __builtin_amdgcn_global_load_lds((cg_void*)(gA + koff),
                (lds_void*)(lds + sb + w * 2048), 16, 0, 0);
            __builtin_amdgcn_global_load_lds((cg_void*)(gA1 + 8 * K_DIM + koff),
                (lds_void*)(lds + sb + w * 2048 + 1024), 16, 0, 0);
            // outstanding: 2 (this tile's DMA) + 4 B + 2 DMA = 8; drain the 2 oldest
            asm volatile("s_waitcnt vmcnt(6)" ::: "memory");
        } else {
            asm volatile("s_waitcnt vmcnt(4)" ::: "memory");  // drain DMA, B stays in flight
        }
        __builtin_amdgcn_s_barrier();          // buf c ready

        #pragma unroll
        for (int mb = 0; mb < 2; ++mb) af0[mb] = LD16(aBase + c + mb * 4096 + aS0);
        #pragma unroll
        for (int mb = 0; mb < 2; ++mb) af1[mb] = LD16(aBase + c + mb * 4096 + aS1);
        // compiler inserts exact lgkmcnt for af* and vmcnt for bc* before first use
        __builtin_amdgcn_s_setprio(1);
        #pragma unroll
        for (int mb = 0; mb < 2; ++mb)
            #pragma unroll
            for (int nb = 0; nb < 2; ++nb)
                acc[mb][nb] = __builtin_amdgcn_mfma_i32_32x32x32_i8(af0[mb], bc[nb][0],
                                                                    acc[mb][nb], 0, 0, 0);
        #pragma unroll
        for (int mb = 0; mb < 2; ++mb)
            #pragma unroll
            for (int nb = 0; nb < 2; ++nb)
                acc[mb][nb] = __builtin_amdgcn_mfma_i32_32x32x32_i8(af1[mb], bc[nb][1],
                                                                    acc[mb][nb], 0, 0, 0);
        __builtin_amdgcn_s_setprio(0);
        __builtin_amdgcn_s_barrier();          // all waves done reading buf c
    }

    const int colbase = bn + wc * 64;
    float bi[2];
    #pragma unroll
    for (int nb = 0; nb < 2; ++nb) bi[nb] = bias[colbase + nb * 32 + r32];
    #pragma unroll
    for (int mb = 0; mb < 2; ++mb) {
        #pragma unroll
        for (int nb = 0; nb < 2; ++nb) {
            #pragma unroll
            for (int r = 0; r < 16; ++r) {
                // C/D 32x32: col = lane&31, row = (r&3) + 8*(r>>2) + 4*(lane>>5)
                int row = bm + wr * 64 + mb * 32 + (r & 3) + 8 * (r >> 2) + 4 * hi;
                int col = colbase + nb * 32 + r32;
                C[(size_t)row * N_DIM + col] = (float)acc[mb][nb][r] * scale + bi[nb];
            }
        }
    }
}

extern "C" void kernel_launch(void* const* d_in, const int* in_sizes, int n_in,
                              void* d_out, int out_size, void* d_ws, size_t ws_size,
                              hipStream_t stream) {
    const float* x = (const float*)d_in[0];
    const float* wts = (const float*)d_in[1];
    const float* bias = (const float*)d_in[2];
    float* out = (float*)d_out;

    char* ws = (char*)d_ws;
    unsigned* scal = (unsigned*)ws;                       // 64 B
    double2* part = (double2*)(ws + 1024);                // 16 KB
    float* mu = (float*)(ws + 32768);                     // 32 KB
    float* rstd = (float*)(ws + 65536);                   // 32 KB
    float* rowmax = (float*)(ws + 98304);                 // 32 KB
    signed char* q = (signed char*)(ws + 131072);         // 16 MB
    signed char* wq = (signed char*)(ws + 131072 + 16777216);  // 16 MB

    hipLaunchKernelGGL(pass1, dim3(9216), dim3(256), 0, stream,
                       x, (const float4*)wts, mu, rstd, rowmax, part);
    hipLaunchKernelGGL(wred2, dim3(1), dim3(256), 0, stream, part, rowmax, scal);
    hipLaunchKernelGGL(pass2, dim3(9216), dim3(256), 0, stream,
                       x, (const float4*)wts, mu, rstd, scal, q, (int4*)wq);
    hipLaunchKernelGGL(gemm_i8, dim3(2048), dim3(512), 0, stream,
                       q, wq, bias, scal, out);
}

// Round 10
// 234.526 us; speedup vs baseline: 1.5756x; 1.5756x over previous
//
#include <hip/hip_runtime.h>

// BitLinear: LN (no affine) -> global absmax int8 quant -> q @ sign(W-mean(W))^T
//   -> * (maxval/128 * mean|W|) + bias
// x: [4,2048,2048] f32 -> M=8192,K=2048 ; W: [8192,2048] -> N=8192 ; out f32 [8192,8192]

using i32x4 = __attribute__((ext_vector_type(4))) int;
using i32x16 = __attribute__((ext_vector_type(16))) int;

typedef const __attribute__((address_space(1))) void cg_void;
typedef __attribute__((address_space(3))) void lds_void;

#define K_DIM 2048
#define N_DIM 8192
#define M_DIM 8192
#define NELEM_W 16777216   // 8192*2048

// ws layout: scal@0 ([0]=absmax f32, [1]=wmean, [2]=beta); part@1024; mu@32768;
//            rstd@65536; rowmax@98304; q@131072; wq@131072+16M

// ---- fused pass1: W sum/abs-sum partials (blocks 0..1023) + LN stats (1024..9215) ----
__global__ __launch_bounds__(256) void pass1(const float* __restrict__ x,
                                             const float4* __restrict__ w4,
                                             float* __restrict__ mu_arr,
                                             float* __restrict__ rstd_arr,
                                             float* __restrict__ rowmax,
                                             double2* __restrict__ part) {
    __shared__ double sbd[8];
    __shared__ float sb1[4];
    __shared__ float sb2[8];
    const int bid = blockIdx.x, t = threadIdx.x;
    const int lane = t & 63, wv = t >> 6;
    if (bid < 1024) {
        double s = 0.0, a = 0.0;
        for (int i = bid * 256 + t; i < NELEM_W / 4; i += 1024 * 256) {
            float4 v = w4[i];
            s += (double)v.x + (double)v.y + (double)v.z + (double)v.w;
            a += fabs((double)v.x) + fabs((double)v.y) + fabs((double)v.z) + fabs((double)v.w);
        }
        for (int o = 32; o; o >>= 1) { s += __shfl_xor(s, o); a += __shfl_xor(a, o); }
        if (lane == 0) { sbd[wv] = s; sbd[4 + wv] = a; }
        __syncthreads();
        if (t == 0) {
            double2 r;
            r.x = sbd[0] + sbd[1] + sbd[2] + sbd[3];
            r.y = sbd[4] + sbd[5] + sbd[6] + sbd[7];
            part[bid] = r;
        }
    } else {
        const int row = bid - 1024;
        const float4* xr = (const float4*)x + (size_t)row * 512;
        float4 v0 = xr[t], v1 = xr[t + 256];
        float s = v0.x + v0.y + v0.z + v0.w + v1.x + v1.y + v1.z + v1.w;
        for (int o = 32; o; o >>= 1) s += __shfl_xor(s, o);
        if (lane == 0) sb1[wv] = s;
        __syncthreads();
        float mu = (sb1[0] + sb1[1] + sb1[2] + sb1[3]) * (1.0f / 2048.0f);
        float ssq = 0.f, md = 0.f, d;
        d = v0.x - mu; ssq += d * d; md = fmaxf(md, fabsf(d));
        d = v0.y - mu; ssq += d * d; md = fmaxf(md, fabsf(d));
        d = v0.z - mu; ssq += d * d; md = fmaxf(md, fabsf(d));
        d = v0.w - mu; ssq += d * d; md = fmaxf(md, fabsf(d));
        d = v1.x - mu; ssq += d * d; md = fmaxf(md, fabsf(d));
        d = v1.y - mu; ssq += d * d; md = fmaxf(md, fabsf(d));
        d = v1.z - mu; ssq += d * d; md = fmaxf(md, fabsf(d));
        d = v1.w - mu; ssq += d * d; md = fmaxf(md, fabsf(d));
        for (int o = 32; o; o >>= 1) {
            ssq += __shfl_xor(ssq, o);
            md = fmaxf(md, __shfl_xor(md, o));
        }
        if (lane == 0) { sb2[wv] = ssq; sb2[4 + wv] = md; }
        __syncthreads();
        if (t == 0) {
            float var = (sb2[0] + sb2[1] + sb2[2] + sb2[3]) * (1.0f / 2048.0f);
            float rstd = 1.0f / sqrtf(var + 1e-5f);
            mu_arr[row] = mu;
            rstd_arr[row] = rstd;
            rowmax[row] = fmaxf(fmaxf(sb2[4], sb2[5]), fmaxf(sb2[6], sb2[7])) * rstd;
        }
    }
}

// ---- wred2: finalize wmean/beta + global absmax ----
__global__ __launch_bounds__(256) void wred2(const double2* __restrict__ part,
                                             const float* __restrict__ rowmax,
                                             unsigned* __restrict__ scal) {
    double s = 0.0, a = 0.0;
    float m = 0.f;
    const int t = threadIdx.x, lane = t & 63, wv = t >> 6;
    for (int i = t; i < 1024; i += 256) { double2 p = part[i]; s += p.x; a += p.y; }
    for (int i = t; i < 8192; i += 256) m = fmaxf(m, rowmax[i]);
    for (int o = 32; o; o >>= 1) {
        s += __shfl_xor(s, o); a += __shfl_xor(a, o);
        m = fmaxf(m, __shfl_xor(m, o));
    }
    __shared__ double sbd[8];
    __shared__ float sbm[4];
    if (lane == 0) { sbd[wv] = s; sbd[4 + wv] = a; sbm[wv] = m; }
    __syncthreads();
    if (t == 0) {
        double st = sbd[0] + sbd[1] + sbd[2] + sbd[3];
        double at = sbd[4] + sbd[5] + sbd[6] + sbd[7];
        ((float*)scal)[0] = fmaxf(fmaxf(sbm[0], sbm[1]), fmaxf(sbm[2], sbm[3]));
        ((float*)scal)[1] = (float)(st / (double)NELEM_W);  // wmean
        ((float*)scal)[2] = (float)(at / (double)NELEM_W);  // beta
    }
}

// ---- fused pass2: quant_w (blocks 0..1023) + quant_x (1024..9215) ----
__device__ __forceinline__ int sgn8(float d) { return (d > 0.f) ? 1 : ((d < 0.f) ? -1 : 0); }

__global__ __launch_bounds__(256) void pass2(const float* __restrict__ x,
                                             const float4* __restrict__ w4,
                                             const float* __restrict__ mu_arr,
                                             const float* __restrict__ rstd_arr,
                                             const unsigned* __restrict__ scal,
                                             signed char* __restrict__ q,
                                             int4* __restrict__ wq4) {
    const int bid = blockIdx.x, t = threadIdx.x;
    if (bid < 1024) {
        float wm = ((const float*)scal)[1];
        for (int i = bid * 256 + t; i < NELEM_W / 16; i += 1024 * 256) {
            int words[4];
            #pragma unroll
            for (int jj = 0; jj < 4; ++jj) {
                float4 v = w4[i * 4 + jj];
                int b0 = sgn8(v.x - wm) & 255, b1 = sgn8(v.y - wm) & 255;
                int b2 = sgn8(v.z - wm) & 255, b3 = sgn8(v.w - wm) & 255;
                words[jj] = b0 | (b1 << 8) | (b2 << 16) | (b3 << 24);
            }
            wq4[i] = make_int4(words[0], words[1], words[2], words[3]);
        }
    } else {
        const int row = bid - 1024;
        float mu = mu_arr[row], rstd = rstd_arr[row];
        float s = 128.0f / ((const float*)scal)[0];
        const float4* xr = (const float4*)x + (size_t)row * 512;
        float4 v0 = xr[2 * t], v1 = xr[2 * t + 1];
        float xs[8] = {v0.x, v0.y, v0.z, v0.w, v1.x, v1.y, v1.z, v1.w};
        int b[8];
        #pragma unroll
        for (int j = 0; j < 8; ++j) {
            float norm = (xs[j] - mu) * rstd;
            int qi = (int)rintf(norm * s);   // half-even == jnp.round; +128 wraps via &255
            b[j] = qi & 255;
        }
        int w0 = b[0] | (b[1] << 8) | (b[2] << 16) | (b[3] << 24);
        int w1 = b[4] | (b[5] << 8) | (b[6] << 16) | (b[7] << 24);
        ((int2*)(q + (size_t)row * 2048))[t] = make_int2(w0, w1);
    }
}

// ---- int8 GEMM v10: r6 geometry + 80B-padded LDS rows (stride-5 quads, no swizzle) ----
// 256x128 tile, BK=64, 8 waves (4Mx2N), wave 64x64 = 2x2 of 32x32x32, 2 blocks/CU.
// LDS row stride 80B (64B data + 16B pad): quad(row,slot) = (5*row + slot) mod 8; 5 odd
// => any 8 consecutive rows cover 8 distinct bank-quads at fixed slot — kills the
// stride-4 aliasing every column-XOR left intact. DMA dest stays wave-linear (1KB
// chunks); per-lane source does the /5 row-col mapping (pad slots remapped in-bounds).
// B back in LDS (r9 falsified direct-global B: 64-line gathers choke vmem issue).
#define LD16(p) (*(const i32x4*)(p))
#define BUF_BYTES 32768    // A 20480 + B 12288 (incl pad) per buffer

__global__ __launch_bounds__(512, 4) void gemm_i8(const signed char* __restrict__ A,
                                                  const signed char* __restrict__ B,
                                                  const float* __restrict__ bias,
                                                  const unsigned* __restrict__ scal,
                                                  float* __restrict__ C) {
    __shared__ alignas(16) char lds[65536];    // 2 x 32KB
    const int t = threadIdx.x, w = t >> 6, lane = t & 63;

    // grid 2048 = 8 XCD x (4 m-panels x 64 n); A panel (512 KB) stays L2-hot per XCD.
    const int wg = blockIdx.x;
    const int xcd = wg & 7, idx = wg >> 3;
    const int bm = (xcd * 4 + (idx >> 6)) * 256;
    const int bn = (idx & 63) * 128;

    const int wr = w >> 1, wc = w & 1;         // wave grid 4M x 2N
    const int r32 = lane & 31, hi = lane >> 5; // 32x32 fragment coords

    // ---- staging: 32 chunks of 1KB (A: 0..19, B: 20..31; 30,31 pure pad) ----
    // chunk c, lane l: LDS bytes c*1024 + l*16 -> row = (64c+l)/5, slot=(64c+l)%5.
    // slot 4 = pad (source remapped to slot 0, same row — benign duplicate).
    const signed char* gsrc[4];
    int ldso[4];
    #pragma unroll
    for (int j = 0; j < 4; ++j) {
        const int c = w + 8 * j;
        ldso[j] = c * 1024;
        if (c < 20) {
            const int v = 64 * c + lane;
            const int row = v / 5;
            const int col = (v - 5 * row) & 3;         // slot4 -> 0
            gsrc[j] = A + (size_t)(bm + row) * K_DIM + col * 16;
        } else {
            const int v = 64 * (c - 20) + lane;
            int row = v / 5;
            if (row > 127) row = 127;                  // pad chunks stay in-bounds
            const int col = (v - 5 * (v / 5)) & 3;
            gsrc[j] = B + (size_t)(bn + row) * K_DIM + col * 16;
        }
    }

    // ---- fragment read bases (80B row stride, no swizzle) ----
    // A row = wr*64 + mb*32 + r32; B row = wc*64 + nb*32 + r32; off = ks*32 + hi*16
    const char* aBase = lds + (wr * 64 + r32) * 80;
    const char* bBase = lds + 20480 + (wc * 64 + r32) * 80;
    const int k0 = hi * 16;          // ks=0
    const int k1 = 32 + hi * 16;     // ks=1

    const float scale = (((const float*)scal)[0] * (1.0f / 128.0f)) * ((const float*)scal)[2];

    i32x16 acc[2][2] = {};
    i32x4 a0[2], a1[2], b0[2], b1[2];

    // prologue: tile 0 -> buf0 (4 loads/wave in flight)
    #pragma unroll
    for (int j = 0; j < 4; ++j)
        __builtin_amdgcn_global_load_lds((cg_void*)(gsrc[j]),
            (lds_void*)(lds + ldso[j]), 16, 0, 0);

    #pragma unroll 2
    for (int kt = 0; kt < 32; ++kt) {
        const int c = (kt & 1) * BUF_BYTES;
        if (kt < 31) {
            const int koff = (kt + 1) * 64;
            const int sb = ((kt + 1) & 1) * BUF_BYTES;
            #pragma unroll
            for (int j = 0; j < 4; ++j)
                __builtin_amdgcn_global_load_lds((cg_void*)(gsrc[j] + koff),
                    (lds_void*)(lds + sb + ldso[j]), 16, 0, 0);
            asm volatile("s_waitcnt vmcnt(4)" ::: "memory");  // this tile's 4 landed
        } else {
            asm volatile("s_waitcnt vmcnt(0)" ::: "memory");
        }
        __builtin_amdgcn_s_barrier();          // buf c ready

        #pragma unroll
        for (int mb = 0; mb < 2; ++mb) a0[mb] = LD16(aBase + c + mb * 2560 + k0);
        #pragma unroll
        for (int nb = 0; nb < 2; ++nb) b0[nb] = LD16(bBase + c + nb * 2560 + k0);
        #pragma unroll
        for (int mb = 0; mb < 2; ++mb) a1[mb] = LD16(aBase + c + mb * 2560 + k1);
        #pragma unroll
        for (int nb = 0; nb < 2; ++nb) b1[nb] = LD16(bBase + c + nb * 2560 + k1);
        __builtin_amdgcn_s_setprio(1);
        #pragma unroll
        for (int mb = 0; mb < 2; ++mb)
            #pragma unroll
            for (int nb = 0; nb < 2; ++nb)
                acc[mb][nb] = __builtin_amdgcn_mfma_i32_32x32x32_i8(a0[mb], b0[nb],
                                                                    acc[mb][nb], 0, 0, 0);
        #pragma unroll
        for (int mb = 0; mb < 2; ++mb)
            #pragma unroll
            for (int nb = 0; nb < 2; ++nb)
                acc[mb][nb] = __builtin_amdgcn_mfma_i32_32x32x32_i8(a1[mb], b1[nb],
                                                                    acc[mb][nb], 0, 0, 0);
        __builtin_amdgcn_s_setprio(0);
        __builtin_amdgcn_s_barrier();          // all waves done reading buf c
    }

    const int colbase = bn + wc * 64;
    float bi[2];
    #pragma unroll
    for (int nb = 0; nb < 2; ++nb) bi[nb] = bias[colbase + nb * 32 + r32];
    #pragma unroll
    for (int mb = 0; mb < 2; ++mb) {
        #pragma unroll
        for (int nb = 0; nb < 2; ++nb) {
            #pragma unroll
            for (int r = 0; r < 16; ++r) {
                // C/D 32x32: col = lane&31, row = (r&3) + 8*(r>>2) + 4*(lane>>5)
                int row = bm + wr * 64 + mb * 32 + (r & 3) + 8 * (r >> 2) + 4 * hi;
                int col = colbase + nb * 32 + r32;
                C[(size_t)row * N_DIM + col] = (float)acc[mb][nb][r] * scale + bi[nb];
            }
        }
    }
}

extern "C" void kernel_launch(void* const* d_in, const int* in_sizes, int n_in,
                              void* d_out, int out_size, void* d_ws, size_t ws_size,
                              hipStream_t stream) {
    const float* x = (const float*)d_in[0];
    const float* wts = (const float*)d_in[1];
    const float* bias = (const float*)d_in[2];
    float* out = (float*)d_out;

    char* ws = (char*)d_ws;
    unsigned* scal = (unsigned*)ws;                       // 64 B
    double2* part = (double2*)(ws + 1024);                // 16 KB
    float* mu = (float*)(ws + 32768);                     // 32 KB
    float* rstd = (float*)(ws + 65536);                   // 32 KB
    float* rowmax = (float*)(ws + 98304);                 // 32 KB
    signed char* q = (signed char*)(ws + 131072);         // 16 MB
    signed char* wq = (signed char*)(ws + 131072 + 16777216);  // 16 MB

    hipLaunchKernelGGL(pass1, dim3(9216), dim3(256), 0, stream,
                       x, (const float4*)wts, mu, rstd, rowmax, part);
    hipLaunchKernelGGL(wred2, dim3(1), dim3(256), 0, stream, part, rowmax, scal);
    hipLaunchKernelGGL(pass2, dim3(9216), dim3(256), 0, stream,
                       x, (const float4*)wts, mu, rstd, scal, q, (int4*)wq);
    hipLaunchKernelGGL(gemm_i8, dim3(2048), dim3(512), 0, stream,
                       q, wq, bias, scal, out);
}

// Round 11
// 228.589 us; speedup vs baseline: 1.6165x; 1.0260x over previous
//
#include <hip/hip_runtime.h>

// BitLinear: LN (no affine) -> global absmax int8 quant -> q @ sign(W-mean(W))^T
//   -> * (maxval/128 * mean|W|) + bias
// x: [4,2048,2048] f32 -> M=8192,K=2048 ; W: [8192,2048] -> N=8192 ; out f32 [8192,8192]

using i32x4 = __attribute__((ext_vector_type(4))) int;
using i32x16 = __attribute__((ext_vector_type(16))) int;

typedef const __attribute__((address_space(1))) void cg_void;
typedef __attribute__((address_space(3))) void lds_void;

#define K_DIM 2048
#define N_DIM 8192
#define M_DIM 8192
#define NELEM_W 16777216   // 8192*2048

// ws layout: scal@0 ([0]=absmax f32, [1]=wmean, [2]=beta); part@1024; mu@32768;
//            rstd@65536; rowmax@98304; q@131072; wq@131072+16M

// ---- fused pass1: W sum/abs-sum partials (blocks 0..1023) + LN stats (1024..9215) ----
__global__ __launch_bounds__(256) void pass1(const float* __restrict__ x,
                                             const float4* __restrict__ w4,
                                             float* __restrict__ mu_arr,
                                             float* __restrict__ rstd_arr,
                                             float* __restrict__ rowmax,
                                             double2* __restrict__ part) {
    __shared__ double sbd[8];
    __shared__ float sb1[4];
    __shared__ float sb2[8];
    const int bid = blockIdx.x, t = threadIdx.x;
    const int lane = t & 63, wv = t >> 6;
    if (bid < 1024) {
        double s = 0.0, a = 0.0;
        for (int i = bid * 256 + t; i < NELEM_W / 4; i += 1024 * 256) {
            float4 v = w4[i];
            s += (double)v.x + (double)v.y + (double)v.z + (double)v.w;
            a += fabs((double)v.x) + fabs((double)v.y) + fabs((double)v.z) + fabs((double)v.w);
        }
        for (int o = 32; o; o >>= 1) { s += __shfl_xor(s, o); a += __shfl_xor(a, o); }
        if (lane == 0) { sbd[wv] = s; sbd[4 + wv] = a; }
        __syncthreads();
        if (t == 0) {
            double2 r;
            r.x = sbd[0] + sbd[1] + sbd[2] + sbd[3];
            r.y = sbd[4] + sbd[5] + sbd[6] + sbd[7];
            part[bid] = r;
        }
    } else {
        const int row = bid - 1024;
        const float4* xr = (const float4*)x + (size_t)row * 512;
        float4 v0 = xr[t], v1 = xr[t + 256];
        float s = v0.x + v0.y + v0.z + v0.w + v1.x + v1.y + v1.z + v1.w;
        for (int o = 32; o; o >>= 1) s += __shfl_xor(s, o);
        if (lane == 0) sb1[wv] = s;
        __syncthreads();
        float mu = (sb1[0] + sb1[1] + sb1[2] + sb1[3]) * (1.0f / 2048.0f);
        float ssq = 0.f, md = 0.f, d;
        d = v0.x - mu; ssq += d * d; md = fmaxf(md, fabsf(d));
        d = v0.y - mu; ssq += d * d; md = fmaxf(md, fabsf(d));
        d = v0.z - mu; ssq += d * d; md = fmaxf(md, fabsf(d));
        d = v0.w - mu; ssq += d * d; md = fmaxf(md, fabsf(d));
        d = v1.x - mu; ssq += d * d; md = fmaxf(md, fabsf(d));
        d = v1.y - mu; ssq += d * d; md = fmaxf(md, fabsf(d));
        d = v1.z - mu; ssq += d * d; md = fmaxf(md, fabsf(d));
        d = v1.w - mu; ssq += d * d; md = fmaxf(md, fabsf(d));
        for (int o = 32; o; o >>= 1) {
            ssq += __shfl_xor(ssq, o);
            md = fmaxf(md, __shfl_xor(md, o));
        }
        if (lane == 0) { sb2[wv] = ssq; sb2[4 + wv] = md; }
        __syncthreads();
        if (t == 0) {
            float var = (sb2[0] + sb2[1] + sb2[2] + sb2[3]) * (1.0f / 2048.0f);
            float rstd = 1.0f / sqrtf(var + 1e-5f);
            mu_arr[row] = mu;
            rstd_arr[row] = rstd;
            rowmax[row] = fmaxf(fmaxf(sb2[4], sb2[5]), fmaxf(sb2[6], sb2[7])) * rstd;
        }
    }
}

// ---- wred2: finalize wmean/beta + global absmax ----
__global__ __launch_bounds__(256) void wred2(const double2* __restrict__ part,
                                             const float* __restrict__ rowmax,
                                             unsigned* __restrict__ scal) {
    double s = 0.0, a = 0.0;
    float m = 0.f;
    const int t = threadIdx.x, lane = t & 63, wv = t >> 6;
    for (int i = t; i < 1024; i += 256) { double2 p = part[i]; s += p.x; a += p.y; }
    for (int i = t; i < 8192; i += 256) m = fmaxf(m, rowmax[i]);
    for (int o = 32; o; o >>= 1) {
        s += __shfl_xor(s, o); a += __shfl_xor(a, o);
        m = fmaxf(m, __shfl_xor(m, o));
    }
    __shared__ double sbd[8];
    __shared__ float sbm[4];
    if (lane == 0) { sbd[wv] = s; sbd[4 + wv] = a; sbm[wv] = m; }
    __syncthreads();
    if (t == 0) {
        double st = sbd[0] + sbd[1] + sbd[2] + sbd[3];
        double at = sbd[4] + sbd[5] + sbd[6] + sbd[7];
        ((float*)scal)[0] = fmaxf(fmaxf(sbm[0], sbm[1]), fmaxf(sbm[2], sbm[3]));
        ((float*)scal)[1] = (float)(st / (double)NELEM_W);  // wmean
        ((float*)scal)[2] = (float)(at / (double)NELEM_W);  // beta
    }
}

// ---- fused pass2: quant_w (blocks 0..1023) + quant_x (1024..9215) ----
__device__ __forceinline__ int sgn8(float d) { return (d > 0.f) ? 1 : ((d < 0.f) ? -1 : 0); }

__global__ __launch_bounds__(256) void pass2(const float* __restrict__ x,
                                             const float4* __restrict__ w4,
                                             const float* __restrict__ mu_arr,
                                             const float* __restrict__ rstd_arr,
                                             const unsigned* __restrict__ scal,
                                             signed char* __restrict__ q,
                                             int4* __restrict__ wq4) {
    const int bid = blockIdx.x, t = threadIdx.x;
    if (bid < 1024) {
        float wm = ((const float*)scal)[1];
        for (int i = bid * 256 + t; i < NELEM_W / 16; i += 1024 * 256) {
            int words[4];
            #pragma unroll
            for (int jj = 0; jj < 4; ++jj) {
                float4 v = w4[i * 4 + jj];
                int b0 = sgn8(v.x - wm) & 255, b1 = sgn8(v.y - wm) & 255;
                int b2 = sgn8(v.z - wm) & 255, b3 = sgn8(v.w - wm) & 255;
                words[jj] = b0 | (b1 << 8) | (b2 << 16) | (b3 << 24);
            }
            wq4[i] = make_int4(words[0], words[1], words[2], words[3]);
        }
    } else {
        const int row = bid - 1024;
        float mu = mu_arr[row], rstd = rstd_arr[row];
        float s = 128.0f / ((const float*)scal)[0];
        const float4* xr = (const float4*)x + (size_t)row * 512;
        float4 v0 = xr[2 * t], v1 = xr[2 * t + 1];
        float xs[8] = {v0.x, v0.y, v0.z, v0.w, v1.x, v1.y, v1.z, v1.w};
        int b[8];
        #pragma unroll
        for (int j = 0; j < 8; ++j) {
            float norm = (xs[j] - mu) * rstd;
            int qi = (int)rintf(norm * s);   // half-even == jnp.round; +128 wraps via &255
            b[j] = qi & 255;
        }
        int w0 = b[0] | (b[1] << 8) | (b[2] << 16) | (b[3] << 24);
        int w1 = b[4] | (b[5] << 8) | (b[6] << 16) | (b[7] << 24);
        ((int2*)(q + (size_t)row * 2048))[t] = make_int2(w0, w1);
    }
}

// ---- int8 GEMM v11: r6 geometry + TRI-buffer depth-2 prefetch (counted vmcnt(6)) ----
// 256x128 tile, BK=64, 8 waves (4Mx2N), wave 64x64 = 2x2 of 32x32x32, 72KB LDS,
// 2 blocks/CU. Pipeline: prologue stages tiles 0,1; at top of tile k issue tile k+2
// into the slot freed by tile k-1's trailing barrier, then vmcnt(6) -> tiles k+1,k+2
// (6 loads) STAY in flight; the wait only confirms tile k. Never drains below 6 until
// the tail. r6's staging/swizzle kept verbatim (r10 proved its 4cyc/read conflict tax
// is non-binding; its 3-loads/thread staging beats r10's padded 4).
#define LD16(p) (*(const i32x4*)(p))
#define TB 24576   // per tile buffer: A 16K + B 8K

#define STAGE(koff, sbase)                                                                  \
    do {                                                                                    \
        __builtin_amdgcn_global_load_lds((cg_void*)(gA + (koff)),                           \
            (lds_void*)(lds + (sbase) + w * 2048), 16, 0, 0);                               \
        __builtin_amdgcn_global_load_lds((cg_void*)(gA + 16 * K_DIM + (koff)),              \
            (lds_void*)(lds + (sbase) + w * 2048 + 1024), 16, 0, 0);                        \
        __builtin_amdgcn_global_load_lds((cg_void*)(gB + (koff)),                           \
            (lds_void*)(lds + (sbase) + 16384 + w * 1024), 16, 0, 0);                       \
    } while (0)

__global__ __launch_bounds__(512, 4) void gemm_i8(const signed char* __restrict__ A,
                                                  const signed char* __restrict__ B,
                                                  const float* __restrict__ bias,
                                                  const unsigned* __restrict__ scal,
                                                  float* __restrict__ C) {
    __shared__ alignas(16) char lds[73728];    // 3 x 24KB
    const int t = threadIdx.x, w = t >> 6, lane = t & 63;

    // grid 2048 = 8 XCD x (4 m-panels x 64 n); A panel (512 KB) stays L2-hot per XCD.
    const int wg = blockIdx.x;
    const int xcd = wg & 7, idx = wg >> 3;
    const int bm = (xcd * 4 + (idx >> 6)) * 256;
    const int bn = (idx & 63) * 128;

    const int wr = w >> 1, wc = w & 1;         // wave grid 4M x 2N
    const int r32 = lane & 31, hi = lane >> 5; // 32x32 fragment coords

    // staging (r6): thread stages 16B; LDS dest wave-linear; global source col carries
    // the involution col ^ (((lane>>3)&3)<<4)
    const int srow = lane >> 2;
    const int scol = ((lane & 3) ^ ((lane >> 3) & 3)) << 4;
    const signed char* gA = A + (size_t)(bm + w * 32 + srow) * K_DIM + scol;
    const signed char* gB = B + (size_t)(bn + w * 16 + srow) * K_DIM + scol;

    // fragment reads (r6 swizzle): A row = wr*64 + mb*32 + r32; B row = wc*64 + nb*32 + r32
    const char* aBase = lds + (wr * 64 + r32) * 64;
    const char* bBase = lds + 16384 + (wc * 64 + r32) * 64;
    const int swz = ((r32 >> 1) & 3) << 4;
    const int sw0 = (hi * 16) ^ swz;           // kstep 0
    const int sw1 = (32 + hi * 16) ^ swz;      // kstep 1

    const float scale = (((const float*)scal)[0] * (1.0f / 128.0f)) * ((const float*)scal)[2];

    i32x16 acc[2][2] = {};
    i32x4 a0[2], a1[2], b0[2], b1[2];

    // tri-buffer rotation: bufC = compute, bufF = in-flight (k+1), bufS = stage (k+2)
    int bufC = 0, bufF = TB, bufS = 2 * TB;

    STAGE(0, 0);            // tile 0 -> buf0
    STAGE(64, TB);          // tile 1 -> buf1   (6 loads in flight)

    for (int kt = 0; kt < 32; ++kt) {
        if (kt < 30) {
            STAGE((kt + 2) * 64, bufS);        // tile k+2 into slot freed by k-1's barrier
            asm volatile("s_waitcnt vmcnt(6)" ::: "memory");   // tile k landed; 6 fly on
        } else if (kt == 30) {
            asm volatile("s_waitcnt vmcnt(3)" ::: "memory");   // tile 30 landed
        } else {
            asm volatile("s_waitcnt vmcnt(0)" ::: "memory");   // tile 31 landed
        }
        __builtin_amdgcn_s_barrier();          // buf bufC ready for all waves

        #pragma unroll
        for (int mb = 0; mb < 2; ++mb) a0[mb] = LD16(aBase + bufC + mb * 2048 + sw0);
        #pragma unroll
        for (int nb = 0; nb < 2; ++nb) b0[nb] = LD16(bBase + bufC + nb * 2048 + sw0);
        #pragma unroll
        for (int mb = 0; mb < 2; ++mb) a1[mb] = LD16(aBase + bufC + mb * 2048 + sw1);
        #pragma unroll
        for (int nb = 0; nb < 2; ++nb) b1[nb] = LD16(bBase + bufC + nb * 2048 + sw1);
        __builtin_amdgcn_s_setprio(1);
        #pragma unroll
        for (int mb = 0; mb < 2; ++mb)
            #pragma unroll
            for (int nb = 0; nb < 2; ++nb)
                acc[mb][nb] = __builtin_amdgcn_mfma_i32_32x32x32_i8(a0[mb], b0[nb],
                                                                    acc[mb][nb], 0, 0, 0);
        #pragma unroll
        for (int mb = 0; mb < 2; ++mb)
            #pragma unroll
            for (int nb = 0; nb < 2; ++nb)
                acc[mb][nb] = __builtin_amdgcn_mfma_i32_32x32x32_i8(a1[mb], b1[nb],
                                                                    acc[mb][nb], 0, 0, 0);
        __builtin_amdgcn_s_setprio(0);
        __builtin_amdgcn_s_barrier();          // all waves done reading bufC -> freeable

        const int rot = bufC; bufC = bufF; bufF = bufS; bufS = rot;
    }

    const int colbase = bn + wc * 64;
    float bi[2];
    #pragma unroll
    for (int nb = 0; nb < 2; ++nb) bi[nb] = bias[colbase + nb * 32 + r32];
    #pragma unroll
    for (int mb = 0; mb < 2; ++mb) {
        #pragma unroll
        for (int nb = 0; nb < 2; ++nb) {
            #pragma unroll
            for (int r = 0; r < 16; ++r) {
                // C/D 32x32: col = lane&31, row = (r&3) + 8*(r>>2) + 4*(lane>>5)
                int row = bm + wr * 64 + mb * 32 + (r & 3) + 8 * (r >> 2) + 4 * hi;
                int col = colbase + nb * 32 + r32;
                C[(size_t)row * N_DIM + col] = (float)acc[mb][nb][r] * scale + bi[nb];
            }
        }
    }
}

extern "C" void kernel_launch(void* const* d_in, const int* in_sizes, int n_in,
                              void* d_out, int out_size, void* d_ws, size_t ws_size,
                              hipStream_t stream) {
    const float* x = (const float*)d_in[0];
    const float* wts = (const float*)d_in[1];
    const float* bias = (const float*)d_in[2];
    float* out = (float*)d_out;

    char* ws = (char*)d_ws;
    unsigned* scal = (unsigned*)ws;                       // 64 B
    double2* part = (double2*)(ws + 1024);                // 16 KB
    float* mu = (float*)(ws + 32768);                     // 32 KB
    float* rstd = (float*)(ws + 65536);                   // 32 KB
    float* rowmax = (float*)(ws + 98304);                 // 32 KB
    signed char* q = (signed char*)(ws + 131072);         // 16 MB
    signed char* wq = (signed char*)(ws + 131072 + 16777216);  // 16 MB

    hipLaunchKernelGGL(pass1, dim3(9216), dim3(256), 0, stream,
                       x, (const float4*)wts, mu, rstd, rowmax, part);
    hipLaunchKernelGGL(wred2, dim3(1), dim3(256), 0, stream, part, rowmax, scal);
    hipLaunchKernelGGL(pass2, dim3(9216), dim3(256), 0, stream,
                       x, (const float4*)wts, mu, rstd, scal, q, (int4*)wq);
    hipLaunchKernelGGL(gemm_i8, dim3(2048), dim3(512), 0, stream,
                       q, wq, bias, scal, out);
}